// Round 3
// baseline (1287.689 us; speedup 1.0000x reference)
//
#include <hip/hip_runtime.h>

#define HH 384
#define WW 384
#define BB 2

typedef unsigned short ushort_t;
typedef short  s16x8 __attribute__((ext_vector_type(8)));
typedef float  f32x4 __attribute__((ext_vector_type(4)));
typedef int    i32x4 __attribute__((ext_vector_type(4)));
typedef int    i32x2 __attribute__((ext_vector_type(2)));

union V16 { i32x4 i4; s16x8 v; ushort_t h[8]; };
union V8  { i32x2 i2; ushort_t h[4]; };

__device__ __forceinline__ ushort_t f2b(float f) {           // RNE fp32->bf16
    unsigned u = __builtin_bit_cast(unsigned, f);
    u += 0x7fffu + ((u >> 16) & 1u);
    return (ushort_t)(u >> 16);
}
__device__ __forceinline__ float b2f(ushort_t h) {
    return __builtin_bit_cast(float, ((unsigned)h) << 16);
}

// ---------------------------------------------------------------------------
// Weight repack.
// Main convs j=0..5: layout [s(2)][t(9)][mt(4)][lane(64)][i(8)], 36864 each.
//   co = mt*16+(lane&15); ci = s*32+(lane>>4)*8+i.
// w_out: [ts(18)=t*2+s][mt(3)][lane][i]: 27648.  w_first: [mt(4)][lane][i]: 2048.
// ---------------------------------------------------------------------------
struct WSrc { const float* p[8]; };

__global__ __launch_bounds__(256)
void repack_k(WSrc ws, ushort_t* __restrict__ Wd)
{
    const int idx = blockIdx.x * 256 + threadIdx.x;
    float val = 0.f;
    if (idx < 221184) {
        const int j = idx / 36864, rem = idx - j * 36864;
        const int i = rem & 7, lane = (rem >> 3) & 63;
        const int f = rem >> 9;                  // 0..71 = (s*9+t)*4+mt
        const int mt = f & 3, st = f >> 2;       // st = s*9+t
        const int t = st % 9, s = st / 9;
        const int co = mt * 16 + (lane & 15);
        const int ci = s * 32 + (lane >> 4) * 8 + i;
        val = ws.p[j][((size_t)(co * 64 + ci)) * 9 + t];
    } else if (idx < 248832) {
        const int rem = idx - 221184;
        const int i = rem & 7, lane = (rem >> 3) & 63;
        const int f = rem >> 9;                  // 0..53 = ts*3+mt, ts=t*2+s
        const int mt = f % 3, ts = f / 3;
        const int s = ts & 1, t = ts >> 1;
        const int co = mt * 16 + (lane & 15);
        const int ci = s * 32 + (lane >> 4) * 8 + i;
        val = (co < 35) ? ws.p[6][((size_t)(co * 64 + ci)) * 9 + t] : 0.f;
    } else {
        const int rem = idx - 248832;            // < 2048
        const int i = rem & 7, lane = (rem >> 3) & 63;
        const int mt = rem >> 9;
        const int co = mt * 16 + (lane & 15);
        const int k = (lane >> 4) * 8 + i;
        if (k < 18) {
            const int ch = (k >= 9) ? 1 : 0;
            const int t = k - ch * 9;
            val = ws.p[7][((size_t)(co * 2 + ch)) * 9 + t];
        }
    }
    if (idx < 250880) Wd[idx] = f2b(val);
}

// ---------------------------------------------------------------------------
// Main conv, implicit GEMM mfma_f32_16x16x32_bf16, NHWC bf16, ci-chunked (2x32)
// staging into a 32 KB LDS union (stage 20.7 KB / transpose-epilogue 32 KB).
// 5 blocks/CU target.
// ---------------------------------------------------------------------------
template<bool RELU, bool RES>
__global__ __launch_bounds__(256, 5)
void conv_mfma(const ushort_t* __restrict__ in, const ushort_t* __restrict__ wp,
               const float* __restrict__ bias, const ushort_t* res,
               ushort_t* __restrict__ out)
{
    __shared__ __align__(16) char smem[32768];
    i32x4* s4 = (i32x4*)smem;                    // stage: 18*4*18 = 1296 x16B

    const int tid = threadIdx.x;
    const int x0 = blockIdx.x * 16, y0 = blockIdx.y * 16, b = blockIdx.z;
    const int lane = tid & 63, w4 = (tid >> 6) * 4;
    const int n = lane & 15, g = lane >> 4;

    f32x4 acc[4][4];
#pragma unroll
    for (int i = 0; i < 4; ++i)
#pragma unroll
        for (int j = 0; j < 4; ++j) acc[i][j] = 0.f;

#pragma unroll
    for (int s = 0; s < 2; ++s) {
        if (s) __syncthreads();                  // chunk0 reads done before overwrite
        // stage ci chunk s: 18x18 halo x 4 octets (16B each)
        for (int idx = tid; idx < 1296; idx += 256) {
            const int oct = idx & 3;
            const int p = idx >> 2;              // 0..323
            const int r = p / 18, xx = p - r * 18;
            const int gy = y0 - 1 + r, gx = x0 - 1 + xx;
            i32x4 v = 0;
            if ((unsigned)gy < HH && (unsigned)gx < WW)
                v = *(const i32x4*)(in + ((size_t)((b * HH + gy) * WW + gx)) * 64
                                       + s * 32 + oct * 8);
            s4[(r * 4 + oct) * 18 + xx] = v;
        }
        __syncthreads();
#pragma unroll
        for (int t = 0; t < 9; ++t) {
            const int ky = t / 3, kx = t - ky * 3;
            V16 af[4];
#pragma unroll
            for (int mt = 0; mt < 4; ++mt)
                af[mt].i4 = *(const i32x4*)(wp +
                    ((size_t)(((s * 9 + t) * 4 + mt) * 64 + lane)) * 8);
            V16 bf[4];
#pragma unroll
            for (int nt = 0; nt < 4; ++nt)
                bf[nt].i4 = s4[((w4 + nt + ky) * 4 + g) * 18 + (n + kx)];
#pragma unroll
            for (int nt = 0; nt < 4; ++nt)
#pragma unroll
                for (int mt = 0; mt < 4; ++mt)
                    acc[nt][mt] = __builtin_amdgcn_mfma_f32_16x16x32_bf16(
                        af[mt].v, bf[nt].v, acc[nt][mt], 0, 0, 0);
        }
    }

    // ---- transpose epilogue ----
    __syncthreads();                             // all s4 reads done; reuse smem
#pragma unroll
    for (int nt = 0; nt < 4; ++nt) {
        const int row = w4 + nt;
#pragma unroll
        for (int mt = 0; mt < 4; ++mt) {
            const int co0 = mt * 16 + g * 4;
            const float4 bv = *(const float4*)(bias + co0);
            float vv[4] = {acc[nt][mt][0] + bv.x, acc[nt][mt][1] + bv.y,
                           acc[nt][mt][2] + bv.z, acc[nt][mt][3] + bv.w};
            if (RES) {
                V8 rv;
                rv.i2 = *(const i32x2*)(res +
                    ((size_t)((b * HH + y0 + row) * WW + x0 + n)) * 64 + co0);
#pragma unroll
                for (int r = 0; r < 4; ++r) vv[r] += b2f(rv.h[r]);
            }
            V8 ov;
#pragma unroll
            for (int r = 0; r < 4; ++r)
                ov.h[r] = f2b(RELU ? fmaxf(vv[r], 0.f) : vv[r]);
            const int c = 2 * mt + (g >> 1);
            const int cpr = c ^ (n & 7);
            *(i32x2*)(smem + row * 2048 + n * 128 + cpr * 16 + (g & 1) * 8) = ov.i2;
        }
    }
    __syncthreads();
    // readback: per wave-instruction 64 lanes x 16B = 1 KB contiguous global
#pragma unroll
    for (int r0 = 0; r0 < 4; ++r0) {
        const int row = w4 + r0, y = y0 + row;
#pragma unroll
        for (int j = 0; j < 2; ++j) {
            const int px = (lane >> 3) + 8 * j;
            const int clin = lane & 7;
            const int cpr = clin ^ (px & 7);
            i32x4 v = *(const i32x4*)(smem + row * 2048 + px * 128 + cpr * 16);
            *(i32x4*)(out + ((size_t)((b * HH + y) * WW + x0 + px)) * 64
                          + clin * 8) = v;
        }
    }
}

// ---------------------------------------------------------------------------
// First conv: CI=2 fp32 NCHW, K=18 padded to 32, transpose epilogue.
// ---------------------------------------------------------------------------
__global__ __launch_bounds__(256, 2)
void conv_first(const float* __restrict__ in, const ushort_t* __restrict__ wp,
                const float* __restrict__ bias, ushort_t* __restrict__ out)
{
    __shared__ float s_raw[2][18][20];
    __shared__ __align__(16) char epi[32768];
    const int tid = threadIdx.x;
    const int x0 = blockIdx.x * 16, y0 = blockIdx.y * 16, b = blockIdx.z;
    for (int idx = tid; idx < 648; idx += 256) {
        const int ch = idx / 324, rem = idx - ch * 324;
        const int r = rem / 18, x = rem - r * 18;
        const int gy = y0 - 1 + r, gx = x0 - 1 + x;
        float v = 0.f;
        if ((unsigned)gy < HH && (unsigned)gx < WW)
            v = in[((size_t)((b * 2 + ch) * HH + gy)) * WW + gx];
        s_raw[ch][r][x] = v;
    }
    __syncthreads();

    const int lane = tid & 63, w4 = (tid >> 6) * 4;
    const int n = lane & 15, g = lane >> 4;

    V16 af[4];
#pragma unroll
    for (int mt = 0; mt < 4; ++mt)
        af[mt].i4 = *(const i32x4*)(wp + ((size_t)(mt * 64 + lane)) * 8);

    f32x4 acc[4][4];
#pragma unroll
    for (int i = 0; i < 4; ++i)
#pragma unroll
        for (int j = 0; j < 4; ++j) acc[i][j] = 0.f;

#pragma unroll
    for (int nt = 0; nt < 4; ++nt) {
        const int r = w4 + nt;
        V16 bf;
#pragma unroll
        for (int i = 0; i < 8; ++i) {
            const int k = g * 8 + i;
            float v = 0.f;
            if (k < 18) {
                const int ch = (k >= 9) ? 1 : 0;
                const int t = k - ch * 9;
                const int ky = t / 3, kx = t - ky * 3;
                v = s_raw[ch][r + ky][n + kx];
            }
            bf.h[i] = f2b(v);
        }
#pragma unroll
        for (int mt = 0; mt < 4; ++mt)
            acc[nt][mt] = __builtin_amdgcn_mfma_f32_16x16x32_bf16(
                af[mt].v, bf.v, acc[nt][mt], 0, 0, 0);
    }

#pragma unroll
    for (int nt = 0; nt < 4; ++nt) {
        const int row = w4 + nt;
#pragma unroll
        for (int mt = 0; mt < 4; ++mt) {
            const int co0 = mt * 16 + g * 4;
            const float4 bv = *(const float4*)(bias + co0);
            V8 ov;
            ov.h[0] = f2b(acc[nt][mt][0] + bv.x);
            ov.h[1] = f2b(acc[nt][mt][1] + bv.y);
            ov.h[2] = f2b(acc[nt][mt][2] + bv.z);
            ov.h[3] = f2b(acc[nt][mt][3] + bv.w);
            const int c = 2 * mt + (g >> 1);
            const int cpr = c ^ (n & 7);
            *(i32x2*)(epi + row * 2048 + n * 128 + cpr * 16 + (g & 1) * 8) = ov.i2;
        }
    }
    __syncthreads();
#pragma unroll
    for (int r0 = 0; r0 < 4; ++r0) {
        const int row = w4 + r0, y = y0 + row;
#pragma unroll
        for (int j = 0; j < 2; ++j) {
            const int px = (lane >> 3) + 8 * j;
            const int clin = lane & 7;
            const int cpr = clin ^ (px & 7);
            i32x4 v = *(const i32x4*)(epi + row * 2048 + px * 128 + cpr * 16);
            *(i32x4*)(out + ((size_t)((b * HH + y) * WW + x0 + px)) * 64
                          + clin * 8) = v;
        }
    }
}

// ---------------------------------------------------------------------------
// KPN radial tables (compile-time)
// ---------------------------------------------------------------------------
template<int W>
struct RTabT {
    int lo[(W - 1) * (W - 1) + 1];
    int mult[(W - 1) * (W - 1) + 1];
    int nin;
    constexpr RTabT() : lo{}, mult{}, nin(0) {
        const int R = W - 1, K = 2 * W - 1, R2 = R * R;
        for (int d2 = 0; d2 <= R2; ++d2) {
            int r = 0;
            while ((r + 1) * (r + 1) <= d2) ++r;
            lo[d2] = r;
        }
        for (int i = 0; i < K; ++i)
            for (int j = 0; j < K; ++j) {
                int d2 = (i - R) * (i - R) + (j - R) * (j - R);
                if (d2 <= R2) { mult[d2]++; nin++; }
            }
    }
};
template<int W> __device__ constexpr RTabT<W> rtab{};

template<int W, int OFF>
struct KpnSec {
    static constexpr int R = W - 1, K = 2 * W - 1, R2 = R * R;
    static __device__ __forceinline__ float run(const float* cv,
                                                const float* s_f, int ty, int tx) {
        float vt[R2 + 1];
        float maxv = 0.f;
#pragma unroll
        for (int d2 = 0; d2 <= R2; ++d2) {
            const int lo = rtab<W>.lo[d2];
            float v;
            if (lo * lo == d2) {
                v = cv[OFF + lo];
            } else {
                const float fr = sqrtf((float)d2) - (float)lo;
                v = fmaf(fr, cv[OFF + lo + 1] - cv[OFF + lo], cv[OFF + lo]);
            }
            vt[d2] = v;
            maxv = fmaxf(maxv, v);
        }
        const float et0 = __expf(-maxv);
#pragma unroll
        for (int d2 = 0; d2 <= R2; ++d2) vt[d2] = __expf(vt[d2] - maxv);
        float den = (float)(K * K - rtab<W>.nin) * et0;
#pragma unroll
        for (int d2 = 0; d2 <= R2; ++d2) {
            const int m = rtab<W>.mult[d2];
            if (m > 0) den = fmaf((float)m, vt[d2], den);
        }
        float num = 0.f;
#pragma unroll
        for (int i = 0; i < K; ++i) {
            const int rb = (ty + 7 + i - R) * 48 + (tx + 7 - R);
#pragma unroll
            for (int j = 0; j < K; ++j) {
                const int d2 = (i - R) * (i - R) + (j - R) * (j - R);
                float e;
                if (d2 <= R2) e = vt[d2]; else e = et0;
                num = fmaf(e, s_f[rb + j], num);
            }
        }
        return num / den;
    }
};

// ---------------------------------------------------------------------------
// Fused out-conv (64->35, COT=3) + KPN. Core never leaves the CU.
// LDS: stage 41472 B (aliased by core px-major 256x37 fp32) + frames 5760 B.
// ---------------------------------------------------------------------------
__global__ __launch_bounds__(256, 3)
void conv_kpn(const ushort_t* __restrict__ in, const ushort_t* __restrict__ wp,
              const float* __restrict__ bias, const float* __restrict__ frames,
              float* __restrict__ out)
{
    __shared__ __align__(16) char smem[41472 + 5760];
    i32x4* s4 = (i32x4*)smem;                    // stage [(r*8+oct)*18+x]
    float* s_core = (float*)smem;                // [px 256][ch 37]
    float* s_f = (float*)(smem + 41472);         // frames 30x48

    const int tid = threadIdx.x;
    const int x0 = blockIdx.x * 16, y0 = blockIdx.y * 16, b = blockIdx.z;

    for (int idx = tid; idx < 2592; idx += 256) {
        const int oct = idx & 7;
        const int p = idx >> 3;
        const int r = p / 18, x = p - r * 18;
        const int gy = y0 - 1 + r, gx = x0 - 1 + x;
        i32x4 v = 0;
        if ((unsigned)gy < HH && (unsigned)gx < WW)
            v = ((const i32x4*)(in + ((size_t)((b * HH + gy) * WW + gx)) * 64))[oct];
        s4[(r * 8 + oct) * 18 + x] = v;
    }
    for (int idx = tid; idx < 900; idx += 256) {
        const int r = idx / 30, c = idx - r * 30;
        const int y = y0 - 7 + r, x = x0 - 7 + c;
        float v = 0.f;
        if ((unsigned)y < HH && (unsigned)x < WW)
            v = frames[((size_t)b * HH + y) * WW + x];
        s_f[r * 48 + c] = v;
    }
    __syncthreads();

    const int lane = tid & 63, w4 = (tid >> 6) * 4;
    const int n = lane & 15, g = lane >> 4;

    f32x4 acc[4][3];
#pragma unroll
    for (int i = 0; i < 4; ++i)
#pragma unroll
        for (int j = 0; j < 3; ++j) acc[i][j] = 0.f;

#pragma unroll
    for (int t = 0; t < 9; ++t) {
        const int ky = t / 3, kx = t - ky * 3;
#pragma unroll
        for (int s = 0; s < 2; ++s) {
            V16 af[3];
#pragma unroll
            for (int mt = 0; mt < 3; ++mt)
                af[mt].i4 = *(const i32x4*)(wp +
                    ((size_t)(((t * 2 + s) * 3 + mt) * 64 + lane)) * 8);
            V16 bf[4];
#pragma unroll
            for (int nt = 0; nt < 4; ++nt)
                bf[nt].i4 = s4[((w4 + nt + ky) * 8 + s * 4 + g) * 18 + (n + kx)];
#pragma unroll
            for (int nt = 0; nt < 4; ++nt)
#pragma unroll
                for (int mt = 0; mt < 3; ++mt)
                    acc[nt][mt] = __builtin_amdgcn_mfma_f32_16x16x32_bf16(
                        af[mt].v, bf[nt].v, acc[nt][mt], 0, 0, 0);
        }
    }

    __syncthreads();                             // stage reads done; write core
#pragma unroll
    for (int nt = 0; nt < 4; ++nt) {
        const int px = (w4 + nt) * 16 + n;
#pragma unroll
        for (int mt = 0; mt < 3; ++mt) {
#pragma unroll
            for (int r = 0; r < 4; ++r) {
                const int ch = mt * 16 + g * 4 + r;
                if (ch < 35)
                    s_core[px * 37 + ch] = fabsf(acc[nt][mt][r] + bias[ch]);
            }
        }
    }
    __syncthreads();

    const int ty = tid >> 4, tx = tid & 15;
    const float* cv = s_core + tid * 37;
    float pred = 0.f;
    pred += KpnSec<2, 0>::run(cv, s_f, ty, tx);
    pred += KpnSec<3, 2>::run(cv, s_f, ty, tx);
    pred += KpnSec<4, 5>::run(cv, s_f, ty, tx);
    pred += KpnSec<5, 9>::run(cv, s_f, ty, tx);
    pred += KpnSec<6, 14>::run(cv, s_f, ty, tx);
    pred += KpnSec<7, 20>::run(cv, s_f, ty, tx);
    pred += KpnSec<8, 27>::run(cv, s_f, ty, tx);
    out[((size_t)b * HH + y0 + ty) * WW + x0 + tx] = pred;
}

// ---------------------------------------------------------------------------
extern "C" void kernel_launch(void* const* d_in, const int* in_sizes, int n_in,
                              void* d_out, int out_size, void* d_ws, size_t ws_size,
                              hipStream_t stream)
{
    const float* est     = (const float*)d_in[0];
    const float* data    = (const float*)d_in[1];
    const float* w_first = (const float*)d_in[2];
    const float* b_first = (const float*)d_in[3];
    const float* w1a = (const float*)d_in[4];
    const float* b1a = (const float*)d_in[5];
    const float* w1b = (const float*)d_in[6];
    const float* b1b = (const float*)d_in[7];
    const float* w2a = (const float*)d_in[8];
    const float* b2a = (const float*)d_in[9];
    const float* w2b = (const float*)d_in[10];
    const float* b2b = (const float*)d_in[11];
    const float* w3a = (const float*)d_in[12];
    const float* b3a = (const float*)d_in[13];
    const float* w3b = (const float*)d_in[14];
    const float* b3b = (const float*)d_in[15];
    const float* w_out = (const float*)d_in[16];
    const float* b_out = (const float*)d_in[17];

    ushort_t* X  = (ushort_t*)d_ws;                         // NHWC bf16 (B,H,W,64)
    ushort_t* T  = X + (size_t)BB * HH * WW * 64;
    ushort_t* Wd = T + (size_t)BB * HH * WW * 64;           // repacked weights

    WSrc wsrc;
    wsrc.p[0] = w1a; wsrc.p[1] = w1b; wsrc.p[2] = w2a; wsrc.p[3] = w2b;
    wsrc.p[4] = w3a; wsrc.p[5] = w3b; wsrc.p[6] = w_out; wsrc.p[7] = w_first;

    dim3 blk(256), g(WW / 16, HH / 16, BB);
    repack_k<<<980, 256, 0, stream>>>(wsrc, Wd);
    conv_first<<<g, blk, 0, stream>>>(est, Wd + 248832, b_first, X);
    conv_mfma<true,  false><<<g, blk, 0, stream>>>(X, Wd + 0,      b1a, nullptr, T);
    conv_mfma<false, true ><<<g, blk, 0, stream>>>(T, Wd + 36864,  b1b, X, X);
    conv_mfma<true,  false><<<g, blk, 0, stream>>>(X, Wd + 73728,  b2a, nullptr, T);
    conv_mfma<false, true ><<<g, blk, 0, stream>>>(T, Wd + 110592, b2b, X, X);
    conv_mfma<true,  false><<<g, blk, 0, stream>>>(X, Wd + 147456, b3a, nullptr, T);
    conv_mfma<false, true ><<<g, blk, 0, stream>>>(T, Wd + 184320, b3b, X, X);
    conv_kpn<<<g, blk, 0, stream>>>(X, Wd + 221184, b_out, data, (float*)d_out);
}

// Round 4
// 602.527 us; speedup vs baseline: 2.1371x; 2.1371x over previous
//
#include <hip/hip_runtime.h>

#define HH 384
#define WW 384
#define BB 2

typedef unsigned short ushort_t;
typedef short  s16x8 __attribute__((ext_vector_type(8)));
typedef float  f32x4 __attribute__((ext_vector_type(4)));
typedef int    i32x4 __attribute__((ext_vector_type(4)));
typedef int    i32x2 __attribute__((ext_vector_type(2)));

union V16 { i32x4 i4; s16x8 v; ushort_t h[8]; };
union V8  { i32x2 i2; ushort_t h[4]; };

__device__ __forceinline__ ushort_t f2b(float f) {           // RNE fp32->bf16
    unsigned u = __builtin_bit_cast(unsigned, f);
    u += 0x7fffu + ((u >> 16) & 1u);
    return (ushort_t)(u >> 16);
}
__device__ __forceinline__ float b2f(ushort_t h) {
    return __builtin_bit_cast(float, ((unsigned)h) << 16);
}

// ---------------------------------------------------------------------------
// Weight repack.
// Main convs j=0..5: layout [s(2)][t(9)][mt(4)][lane(64)][i(8)], 36864 each.
//   co = mt*16+(lane&15); ci = s*32+(lane>>4)*8+i.
// w_out: [ts(18)=t*2+s][mt(3)][lane][i]: 27648.  w_first: [mt(4)][lane][i]: 2048.
// ---------------------------------------------------------------------------
struct WSrc { const float* p[8]; };

__global__ __launch_bounds__(256)
void repack_k(WSrc ws, ushort_t* __restrict__ Wd)
{
    const int idx = blockIdx.x * 256 + threadIdx.x;
    float val = 0.f;
    if (idx < 221184) {
        const int j = idx / 36864, rem = idx - j * 36864;
        const int i = rem & 7, lane = (rem >> 3) & 63;
        const int f = rem >> 9;                  // 0..71 = (s*9+t)*4+mt
        const int mt = f & 3, st = f >> 2;       // st = s*9+t
        const int t = st % 9, s = st / 9;
        const int co = mt * 16 + (lane & 15);
        const int ci = s * 32 + (lane >> 4) * 8 + i;
        val = ws.p[j][((size_t)(co * 64 + ci)) * 9 + t];
    } else if (idx < 248832) {
        const int rem = idx - 221184;
        const int i = rem & 7, lane = (rem >> 3) & 63;
        const int f = rem >> 9;                  // 0..53 = ts*3+mt, ts=t*2+s
        const int mt = f % 3, ts = f / 3;
        const int s = ts & 1, t = ts >> 1;
        const int co = mt * 16 + (lane & 15);
        const int ci = s * 32 + (lane >> 4) * 8 + i;
        val = (co < 35) ? ws.p[6][((size_t)(co * 64 + ci)) * 9 + t] : 0.f;
    } else {
        const int rem = idx - 248832;            // < 2048
        const int i = rem & 7, lane = (rem >> 3) & 63;
        const int mt = rem >> 9;
        const int co = mt * 16 + (lane & 15);
        const int k = (lane >> 4) * 8 + i;
        if (k < 18) {
            const int ch = (k >= 9) ? 1 : 0;
            const int t = k - ch * 9;
            val = ws.p[7][((size_t)(co * 2 + ch)) * 9 + t];
        }
    }
    if (idx < 250880) Wd[idx] = f2b(val);
}

// ---------------------------------------------------------------------------
// Main conv, implicit GEMM mfma_f32_16x16x32_bf16, NHWC bf16, ci-chunked (2x32)
// staging into a 32 KB LDS union (stage 20.7 KB / transpose-epilogue 32 KB).
// __launch_bounds__(256,4): 128-VGPR cap. acc tile alone = 64 VGPRs — do NOT
// constrain tighter (R3 at (256,5) spilled: +570 MB HBM scratch traffic).
// ---------------------------------------------------------------------------
template<bool RELU, bool RES>
__global__ __launch_bounds__(256, 4)
void conv_mfma(const ushort_t* __restrict__ in, const ushort_t* __restrict__ wp,
               const float* __restrict__ bias, const ushort_t* __restrict__ res,
               ushort_t* __restrict__ out)
{
    __shared__ __align__(16) char smem[32768];
    i32x4* s4 = (i32x4*)smem;                    // stage: 18*4*18 = 1296 x16B

    const int tid = threadIdx.x;
    const int x0 = blockIdx.x * 16, y0 = blockIdx.y * 16, b = blockIdx.z;
    const int lane = tid & 63, w4 = (tid >> 6) * 4;
    const int n = lane & 15, g = lane >> 4;

    f32x4 acc[4][4];
#pragma unroll
    for (int i = 0; i < 4; ++i)
#pragma unroll
        for (int j = 0; j < 4; ++j) acc[i][j] = 0.f;

#pragma unroll
    for (int s = 0; s < 2; ++s) {
        if (s) __syncthreads();                  // chunk0 reads done before overwrite
        // stage ci chunk s: 18x18 halo x 4 octets (16B each)
        for (int idx = tid; idx < 1296; idx += 256) {
            const int oct = idx & 3;
            const int p = idx >> 2;              // 0..323
            const int r = p / 18, xx = p - r * 18;
            const int gy = y0 - 1 + r, gx = x0 - 1 + xx;
            i32x4 v = 0;
            if ((unsigned)gy < HH && (unsigned)gx < WW)
                v = *(const i32x4*)(in + ((size_t)((b * HH + gy) * WW + gx)) * 64
                                       + s * 32 + oct * 8);
            s4[(r * 4 + oct) * 18 + xx] = v;
        }
        __syncthreads();
#pragma unroll
        for (int t = 0; t < 9; ++t) {
            const int ky = t / 3, kx = t - ky * 3;
            V16 bf[4];
#pragma unroll
            for (int nt = 0; nt < 4; ++nt)
                bf[nt].i4 = s4[((w4 + nt + ky) * 4 + g) * 18 + (n + kx)];
#pragma unroll
            for (int mt = 0; mt < 4; ++mt) {
                V16 af;
                af.i4 = *(const i32x4*)(wp +
                    ((size_t)(((s * 9 + t) * 4 + mt) * 64 + lane)) * 8);
#pragma unroll
                for (int nt = 0; nt < 4; ++nt)
                    acc[nt][mt] = __builtin_amdgcn_mfma_f32_16x16x32_bf16(
                        af.v, bf[nt].v, acc[nt][mt], 0, 0, 0);
            }
        }
    }

    // ---- transpose epilogue (bias + relu, NO residual here) ----
    __syncthreads();                             // all s4 reads done; reuse smem
#pragma unroll
    for (int nt = 0; nt < 4; ++nt) {
        const int row = w4 + nt;
#pragma unroll
        for (int mt = 0; mt < 4; ++mt) {
            const int co0 = mt * 16 + g * 4;
            const float4 bv = *(const float4*)(bias + co0);
            float vv[4] = {acc[nt][mt][0] + bv.x, acc[nt][mt][1] + bv.y,
                           acc[nt][mt][2] + bv.z, acc[nt][mt][3] + bv.w};
            V8 ov;
#pragma unroll
            for (int r = 0; r < 4; ++r)
                ov.h[r] = f2b(RELU ? fmaxf(vv[r], 0.f) : vv[r]);
            const int c = 2 * mt + (g >> 1);
            const int cpr = c ^ (n & 7);
            *(i32x2*)(smem + row * 2048 + n * 128 + cpr * 16 + (g & 1) * 8) = ov.i2;
        }
    }
    __syncthreads();
    // readback: per wave-instruction 64 lanes x 16B = 1 KB contiguous global.
    // Residual added here so res reads are the same coalesced pattern.
#pragma unroll
    for (int r0 = 0; r0 < 4; ++r0) {
        const int row = w4 + r0, y = y0 + row;
#pragma unroll
        for (int j = 0; j < 2; ++j) {
            const int px = (lane >> 3) + 8 * j;
            const int clin = lane & 7;
            const int cpr = clin ^ (px & 7);
            V16 v;
            v.i4 = *(const i32x4*)(smem + row * 2048 + px * 128 + cpr * 16);
            const size_t goff = ((size_t)((b * HH + y) * WW + x0 + px)) * 64
                                + clin * 8;
            if (RES) {
                V16 rv;
                rv.i4 = *(const i32x4*)(res + goff);
#pragma unroll
                for (int e = 0; e < 8; ++e)
                    v.h[e] = f2b(b2f(v.h[e]) + b2f(rv.h[e]));
            }
            *(i32x4*)(out + goff) = v.i4;
        }
    }
}

// ---------------------------------------------------------------------------
// First conv: CI=2 fp32 NCHW, K=18 padded to 32, transpose epilogue.
// ---------------------------------------------------------------------------
__global__ __launch_bounds__(256, 2)
void conv_first(const float* __restrict__ in, const ushort_t* __restrict__ wp,
                const float* __restrict__ bias, ushort_t* __restrict__ out)
{
    __shared__ float s_raw[2][18][20];
    __shared__ __align__(16) char epi[32768];
    const int tid = threadIdx.x;
    const int x0 = blockIdx.x * 16, y0 = blockIdx.y * 16, b = blockIdx.z;
    for (int idx = tid; idx < 648; idx += 256) {
        const int ch = idx / 324, rem = idx - ch * 324;
        const int r = rem / 18, x = rem - r * 18;
        const int gy = y0 - 1 + r, gx = x0 - 1 + x;
        float v = 0.f;
        if ((unsigned)gy < HH && (unsigned)gx < WW)
            v = in[((size_t)((b * 2 + ch) * HH + gy)) * WW + gx];
        s_raw[ch][r][x] = v;
    }
    __syncthreads();

    const int lane = tid & 63, w4 = (tid >> 6) * 4;
    const int n = lane & 15, g = lane >> 4;

    V16 af[4];
#pragma unroll
    for (int mt = 0; mt < 4; ++mt)
        af[mt].i4 = *(const i32x4*)(wp + ((size_t)(mt * 64 + lane)) * 8);

    f32x4 acc[4][4];
#pragma unroll
    for (int i = 0; i < 4; ++i)
#pragma unroll
        for (int j = 0; j < 4; ++j) acc[i][j] = 0.f;

#pragma unroll
    for (int nt = 0; nt < 4; ++nt) {
        const int r = w4 + nt;
        V16 bf;
#pragma unroll
        for (int i = 0; i < 8; ++i) {
            const int k = g * 8 + i;
            float v = 0.f;
            if (k < 18) {
                const int ch = (k >= 9) ? 1 : 0;
                const int t = k - ch * 9;
                const int ky = t / 3, kx = t - ky * 3;
                v = s_raw[ch][r + ky][n + kx];
            }
            bf.h[i] = f2b(v);
        }
#pragma unroll
        for (int mt = 0; mt < 4; ++mt)
            acc[nt][mt] = __builtin_amdgcn_mfma_f32_16x16x32_bf16(
                af[mt].v, bf.v, acc[nt][mt], 0, 0, 0);
    }

#pragma unroll
    for (int nt = 0; nt < 4; ++nt) {
        const int row = w4 + nt;
#pragma unroll
        for (int mt = 0; mt < 4; ++mt) {
            const int co0 = mt * 16 + g * 4;
            const float4 bv = *(const float4*)(bias + co0);
            V8 ov;
            ov.h[0] = f2b(acc[nt][mt][0] + bv.x);
            ov.h[1] = f2b(acc[nt][mt][1] + bv.y);
            ov.h[2] = f2b(acc[nt][mt][2] + bv.z);
            ov.h[3] = f2b(acc[nt][mt][3] + bv.w);
            const int c = 2 * mt + (g >> 1);
            const int cpr = c ^ (n & 7);
            *(i32x2*)(epi + row * 2048 + n * 128 + cpr * 16 + (g & 1) * 8) = ov.i2;
        }
    }
    __syncthreads();
#pragma unroll
    for (int r0 = 0; r0 < 4; ++r0) {
        const int row = w4 + r0, y = y0 + row;
#pragma unroll
        for (int j = 0; j < 2; ++j) {
            const int px = (lane >> 3) + 8 * j;
            const int clin = lane & 7;
            const int cpr = clin ^ (px & 7);
            i32x4 v = *(const i32x4*)(epi + row * 2048 + px * 128 + cpr * 16);
            *(i32x4*)(out + ((size_t)((b * HH + y) * WW + x0 + px)) * 64
                          + clin * 8) = v;
        }
    }
}

// ---------------------------------------------------------------------------
// KPN radial tables (compile-time)
// ---------------------------------------------------------------------------
template<int W>
struct RTabT {
    int lo[(W - 1) * (W - 1) + 1];
    int mult[(W - 1) * (W - 1) + 1];
    int nin;
    constexpr RTabT() : lo{}, mult{}, nin(0) {
        const int R = W - 1, K = 2 * W - 1, R2 = R * R;
        for (int d2 = 0; d2 <= R2; ++d2) {
            int r = 0;
            while ((r + 1) * (r + 1) <= d2) ++r;
            lo[d2] = r;
        }
        for (int i = 0; i < K; ++i)
            for (int j = 0; j < K; ++j) {
                int d2 = (i - R) * (i - R) + (j - R) * (j - R);
                if (d2 <= R2) { mult[d2]++; nin++; }
            }
    }
};
template<int W> __device__ constexpr RTabT<W> rtab{};

template<int W, int OFF>
struct KpnSec {
    static constexpr int R = W - 1, K = 2 * W - 1, R2 = R * R;
    static __device__ __forceinline__ float run(const float* cv,
                                                const float* s_f, int ty, int tx) {
        float vt[R2 + 1];
        float maxv = 0.f;
#pragma unroll
        for (int d2 = 0; d2 <= R2; ++d2) {
            const int lo = rtab<W>.lo[d2];
            float v;
            if (lo * lo == d2) {
                v = cv[OFF + lo];
            } else {
                const float fr = sqrtf((float)d2) - (float)lo;
                v = fmaf(fr, cv[OFF + lo + 1] - cv[OFF + lo], cv[OFF + lo]);
            }
            vt[d2] = v;
            maxv = fmaxf(maxv, v);
        }
        const float et0 = __expf(-maxv);
#pragma unroll
        for (int d2 = 0; d2 <= R2; ++d2) vt[d2] = __expf(vt[d2] - maxv);
        float den = (float)(K * K - rtab<W>.nin) * et0;
#pragma unroll
        for (int d2 = 0; d2 <= R2; ++d2) {
            const int m = rtab<W>.mult[d2];
            if (m > 0) den = fmaf((float)m, vt[d2], den);
        }
        float num = 0.f;
#pragma unroll
        for (int i = 0; i < K; ++i) {
            const int rb = (ty + 7 + i - R) * 48 + (tx + 7 - R);
#pragma unroll
            for (int j = 0; j < K; ++j) {
                const int d2 = (i - R) * (i - R) + (j - R) * (j - R);
                float e;
                if (d2 <= R2) e = vt[d2]; else e = et0;
                num = fmaf(e, s_f[rb + j], num);
            }
        }
        return num / den;
    }
};

// ---------------------------------------------------------------------------
// Fused out-conv (64->35, COT=3) + KPN. Core never leaves the CU.
// LDS: stage 41472 B (aliased by core px-major 256x37 fp32) + frames 5760 B.
// ---------------------------------------------------------------------------
__global__ __launch_bounds__(256, 3)
void conv_kpn(const ushort_t* __restrict__ in, const ushort_t* __restrict__ wp,
              const float* __restrict__ bias, const float* __restrict__ frames,
              float* __restrict__ out)
{
    __shared__ __align__(16) char smem[41472 + 5760];
    i32x4* s4 = (i32x4*)smem;                    // stage [(r*8+oct)*18+x]
    float* s_core = (float*)smem;                // [px 256][ch 37]
    float* s_f = (float*)(smem + 41472);         // frames 30x48

    const int tid = threadIdx.x;
    const int x0 = blockIdx.x * 16, y0 = blockIdx.y * 16, b = blockIdx.z;

    for (int idx = tid; idx < 2592; idx += 256) {
        const int oct = idx & 7;
        const int p = idx >> 3;
        const int r = p / 18, x = p - r * 18;
        const int gy = y0 - 1 + r, gx = x0 - 1 + x;
        i32x4 v = 0;
        if ((unsigned)gy < HH && (unsigned)gx < WW)
            v = ((const i32x4*)(in + ((size_t)((b * HH + gy) * WW + gx)) * 64))[oct];
        s4[(r * 8 + oct) * 18 + x] = v;
    }
    for (int idx = tid; idx < 900; idx += 256) {
        const int r = idx / 30, c = idx - r * 30;
        const int y = y0 - 7 + r, x = x0 - 7 + c;
        float v = 0.f;
        if ((unsigned)y < HH && (unsigned)x < WW)
            v = frames[((size_t)b * HH + y) * WW + x];
        s_f[r * 48 + c] = v;
    }
    __syncthreads();

    const int lane = tid & 63, w4 = (tid >> 6) * 4;
    const int n = lane & 15, g = lane >> 4;

    f32x4 acc[4][3];
#pragma unroll
    for (int i = 0; i < 4; ++i)
#pragma unroll
        for (int j = 0; j < 3; ++j) acc[i][j] = 0.f;

#pragma unroll
    for (int t = 0; t < 9; ++t) {
        const int ky = t / 3, kx = t - ky * 3;
#pragma unroll
        for (int s = 0; s < 2; ++s) {
            V16 bf[4];
#pragma unroll
            for (int nt = 0; nt < 4; ++nt)
                bf[nt].i4 = s4[((w4 + nt + ky) * 8 + s * 4 + g) * 18 + (n + kx)];
#pragma unroll
            for (int mt = 0; mt < 3; ++mt) {
                V16 af;
                af.i4 = *(const i32x4*)(wp +
                    ((size_t)(((t * 2 + s) * 3 + mt) * 64 + lane)) * 8);
#pragma unroll
                for (int nt = 0; nt < 4; ++nt)
                    acc[nt][mt] = __builtin_amdgcn_mfma_f32_16x16x32_bf16(
                        af.v, bf[nt].v, acc[nt][mt], 0, 0, 0);
            }
        }
    }

    __syncthreads();                             // stage reads done; write core
#pragma unroll
    for (int nt = 0; nt < 4; ++nt) {
        const int px = (w4 + nt) * 16 + n;
#pragma unroll
        for (int mt = 0; mt < 3; ++mt) {
#pragma unroll
            for (int r = 0; r < 4; ++r) {
                const int ch = mt * 16 + g * 4 + r;
                if (ch < 35)
                    s_core[px * 37 + ch] = fabsf(acc[nt][mt][r] + bias[ch]);
            }
        }
    }
    __syncthreads();

    const int ty = tid >> 4, tx = tid & 15;
    const float* cv = s_core + tid * 37;
    float pred = 0.f;
    pred += KpnSec<2, 0>::run(cv, s_f, ty, tx);
    pred += KpnSec<3, 2>::run(cv, s_f, ty, tx);
    pred += KpnSec<4, 5>::run(cv, s_f, ty, tx);
    pred += KpnSec<5, 9>::run(cv, s_f, ty, tx);
    pred += KpnSec<6, 14>::run(cv, s_f, ty, tx);
    pred += KpnSec<7, 20>::run(cv, s_f, ty, tx);
    pred += KpnSec<8, 27>::run(cv, s_f, ty, tx);
    out[((size_t)b * HH + y0 + ty) * WW + x0 + tx] = pred;
}

// ---------------------------------------------------------------------------
extern "C" void kernel_launch(void* const* d_in, const int* in_sizes, int n_in,
                              void* d_out, int out_size, void* d_ws, size_t ws_size,
                              hipStream_t stream)
{
    const float* est     = (const float*)d_in[0];
    const float* data    = (const float*)d_in[1];
    const float* w_first = (const float*)d_in[2];
    const float* b_first = (const float*)d_in[3];
    const float* w1a = (const float*)d_in[4];
    const float* b1a = (const float*)d_in[5];
    const float* w1b = (const float*)d_in[6];
    const float* b1b = (const float*)d_in[7];
    const float* w2a = (const float*)d_in[8];
    const float* b2a = (const float*)d_in[9];
    const float* w2b = (const float*)d_in[10];
    const float* b2b = (const float*)d_in[11];
    const float* w3a = (const float*)d_in[12];
    const float* b3a = (const float*)d_in[13];
    const float* w3b = (const float*)d_in[14];
    const float* b3b = (const float*)d_in[15];
    const float* w_out = (const float*)d_in[16];
    const float* b_out = (const float*)d_in[17];

    ushort_t* X  = (ushort_t*)d_ws;                         // NHWC bf16 (B,H,W,64)
    ushort_t* T  = X + (size_t)BB * HH * WW * 64;
    ushort_t* Wd = T + (size_t)BB * HH * WW * 64;           // repacked weights

    WSrc wsrc;
    wsrc.p[0] = w1a; wsrc.p[1] = w1b; wsrc.p[2] = w2a; wsrc.p[3] = w2b;
    wsrc.p[4] = w3a; wsrc.p[5] = w3b; wsrc.p[6] = w_out; wsrc.p[7] = w_first;

    dim3 blk(256), g(WW / 16, HH / 16, BB);
    repack_k<<<980, 256, 0, stream>>>(wsrc, Wd);
    conv_first<<<g, blk, 0, stream>>>(est, Wd + 248832, b_first, X);
    conv_mfma<true,  false><<<g, blk, 0, stream>>>(X, Wd + 0,      b1a, nullptr, T);
    conv_mfma<false, true ><<<g, blk, 0, stream>>>(T, Wd + 36864,  b1b, X, X);
    conv_mfma<true,  false><<<g, blk, 0, stream>>>(X, Wd + 73728,  b2a, nullptr, T);
    conv_mfma<false, true ><<<g, blk, 0, stream>>>(T, Wd + 110592, b2b, X, X);
    conv_mfma<true,  false><<<g, blk, 0, stream>>>(X, Wd + 147456, b3a, nullptr, T);
    conv_mfma<false, true ><<<g, blk, 0, stream>>>(T, Wd + 184320, b3b, X, X);
    conv_kpn<<<g, blk, 0, stream>>>(X, Wd + 221184, b_out, data, (float*)d_out);
}

// Round 5
// 446.705 us; speedup vs baseline: 2.8826x; 1.3488x over previous
//
#include <hip/hip_runtime.h>

#define HH 384
#define WW 384
#define BB 2

typedef unsigned short ushort_t;
typedef short  s16x8 __attribute__((ext_vector_type(8)));
typedef float  f32x4 __attribute__((ext_vector_type(4)));
typedef int    i32x4 __attribute__((ext_vector_type(4)));
typedef int    i32x2 __attribute__((ext_vector_type(2)));

union V16 { i32x4 i4; s16x8 v; ushort_t h[8]; };
union V8  { i32x2 i2; ushort_t h[4]; };

__device__ __forceinline__ ushort_t f2b(float f) {           // RNE fp32->bf16
    unsigned u = __builtin_bit_cast(unsigned, f);
    u += 0x7fffu + ((u >> 16) & 1u);
    return (ushort_t)(u >> 16);
}
__device__ __forceinline__ float b2f(ushort_t h) {
    return __builtin_bit_cast(float, ((unsigned)h) << 16);
}

// ---------------------------------------------------------------------------
// Weight repack (unchanged from R4).
// Main convs j=0..5: [s(2)][t(9)][mt(4)][lane(64)][i(8)], 36864 each.
// w_out: [ts(18)=t*2+s][mt(3)][lane][i]: 27648.  w_first: [mt(4)][lane][i]: 2048.
// ---------------------------------------------------------------------------
struct WSrc { const float* p[8]; };

__global__ __launch_bounds__(256)
void repack_k(WSrc ws, ushort_t* __restrict__ Wd)
{
    const int idx = blockIdx.x * 256 + threadIdx.x;
    float val = 0.f;
    if (idx < 221184) {
        const int j = idx / 36864, rem = idx - j * 36864;
        const int i = rem & 7, lane = (rem >> 3) & 63;
        const int f = rem >> 9;                  // (s*9+t)*4+mt
        const int mt = f & 3, st = f >> 2;
        const int t = st % 9, s = st / 9;
        const int co = mt * 16 + (lane & 15);
        const int ci = s * 32 + (lane >> 4) * 8 + i;
        val = ws.p[j][((size_t)(co * 64 + ci)) * 9 + t];
    } else if (idx < 248832) {
        const int rem = idx - 221184;
        const int i = rem & 7, lane = (rem >> 3) & 63;
        const int f = rem >> 9;                  // ts*3+mt, ts=t*2+s
        const int mt = f % 3, ts = f / 3;
        const int s = ts & 1, t = ts >> 1;
        const int co = mt * 16 + (lane & 15);
        const int ci = s * 32 + (lane >> 4) * 8 + i;
        val = (co < 35) ? ws.p[6][((size_t)(co * 64 + ci)) * 9 + t] : 0.f;
    } else {
        const int rem = idx - 248832;            // < 2048
        const int i = rem & 7, lane = (rem >> 3) & 63;
        const int mt = rem >> 9;
        const int co = mt * 16 + (lane & 15);
        const int k = (lane >> 4) * 8 + i;
        if (k < 18) {
            const int ch = (k >= 9) ? 1 : 0;
            const int t = k - ch * 9;
            val = ws.p[7][((size_t)(co * 2 + ch)) * 9 + t];
        }
    }
    if (idx < 250880) Wd[idx] = f2b(val);
}

// ---------------------------------------------------------------------------
// Main conv: single-stage 64-ci (41.5 KB LDS), BATCHED staging (11 loads in
// flight), 18 MFMA t-steps, transpose epilogue aliasing the stage buffer.
// (256,4): 128-VGPR cap. acc=64 VGPRs; do NOT constrain tighter (R3 spilled).
// ---------------------------------------------------------------------------
template<bool RELU, bool RES>
__global__ __launch_bounds__(256, 4)
void conv_mfma(const ushort_t* __restrict__ in, const ushort_t* __restrict__ wp,
               const float* __restrict__ bias, const ushort_t* __restrict__ res,
               ushort_t* __restrict__ out)
{
    __shared__ __align__(16) char smem[41472];
    i32x4* s4 = (i32x4*)smem;                    // [(r*8+oct)*18 + x], 2592 slots

    const int tid = threadIdx.x;
    const int x0 = blockIdx.x * 16, y0 = blockIdx.y * 16, b = blockIdx.z;
    const int lane = tid & 63, w4 = (tid >> 6) * 4;
    const int n = lane & 15, g = lane >> 4;

    // ---- batched staging: issue all 11 halo loads, then store to LDS ----
    {
        i32x4 tmp[11];
#pragma unroll
        for (int k = 0; k < 11; ++k) {
            const int idx = tid + k * 256;
            tmp[k] = 0;
            if (idx < 2592) {
                const int oct = idx & 7, p = idx >> 3;
                const int r = p / 18, xx = p - r * 18;
                const int gy = y0 - 1 + r, gx = x0 - 1 + xx;
                if ((unsigned)gy < HH && (unsigned)gx < WW)
                    tmp[k] = *(const i32x4*)(in +
                        ((size_t)((b * HH + gy) * WW + gx)) * 64 + oct * 8);
            }
        }
#pragma unroll
        for (int k = 0; k < 11; ++k) {
            const int idx = tid + k * 256;
            if (idx < 2592) {
                const int oct = idx & 7, p = idx >> 3;
                const int r = p / 18, xx = p - r * 18;
                s4[(r * 8 + oct) * 18 + xx] = tmp[k];
            }
        }
    }
    __syncthreads();

    f32x4 acc[4][4];
#pragma unroll
    for (int i = 0; i < 4; ++i)
#pragma unroll
        for (int j = 0; j < 4; ++j) acc[i][j] = 0.f;

#pragma unroll
    for (int s = 0; s < 2; ++s)
#pragma unroll
    for (int t = 0; t < 9; ++t) {
        const int ky = t / 3, kx = t - ky * 3;
        V16 bf[4];
#pragma unroll
        for (int nt = 0; nt < 4; ++nt)
            bf[nt].i4 = s4[((w4 + nt + ky) * 8 + s * 4 + g) * 18 + (n + kx)];
#pragma unroll
        for (int mt = 0; mt < 4; ++mt) {
            V16 af;
            af.i4 = *(const i32x4*)(wp +
                ((size_t)(((s * 9 + t) * 4 + mt) * 64 + lane)) * 8);
#pragma unroll
            for (int nt = 0; nt < 4; ++nt)
                acc[nt][mt] = __builtin_amdgcn_mfma_f32_16x16x32_bf16(
                    af.v, bf[nt].v, acc[nt][mt], 0, 0, 0);
        }
    }

    // ---- transpose epilogue (aliases stage buffer; 32 KB < 41.5 KB) ----
    __syncthreads();
#pragma unroll
    for (int nt = 0; nt < 4; ++nt) {
        const int row = w4 + nt;
#pragma unroll
        for (int mt = 0; mt < 4; ++mt) {
            const int co0 = mt * 16 + g * 4;
            const float4 bv = *(const float4*)(bias + co0);
            float vv[4] = {acc[nt][mt][0] + bv.x, acc[nt][mt][1] + bv.y,
                           acc[nt][mt][2] + bv.z, acc[nt][mt][3] + bv.w};
            V8 ov;
#pragma unroll
            for (int r = 0; r < 4; ++r)
                ov.h[r] = f2b(RELU ? fmaxf(vv[r], 0.f) : vv[r]);
            const int c = 2 * mt + (g >> 1);
            const int cpr = c ^ (n & 7);
            *(i32x2*)(smem + row * 2048 + n * 128 + cpr * 16 + (g & 1) * 8) = ov.i2;
        }
    }
    __syncthreads();
    // readback: 64 lanes x 16B = 1 KB contiguous per wave instruction;
    // residual added here (same coalesced pattern).
#pragma unroll
    for (int r0 = 0; r0 < 4; ++r0) {
        const int row = w4 + r0, y = y0 + row;
#pragma unroll
        for (int j = 0; j < 2; ++j) {
            const int px = (lane >> 3) + 8 * j;
            const int clin = lane & 7;
            const int cpr = clin ^ (px & 7);
            V16 v;
            v.i4 = *(const i32x4*)(smem + row * 2048 + px * 128 + cpr * 16);
            const size_t goff = ((size_t)((b * HH + y) * WW + x0 + px)) * 64
                                + clin * 8;
            if (RES) {
                V16 rv;
                rv.i4 = *(const i32x4*)(res + goff);
#pragma unroll
                for (int e = 0; e < 8; ++e)
                    v.h[e] = f2b(b2f(v.h[e]) + b2f(rv.h[e]));
            }
            *(i32x4*)(out + goff) = v.i4;
        }
    }
}

// ---------------------------------------------------------------------------
// First conv: CI=2 fp32 NCHW, K=18 padded to 32, transpose epilogue.
// ---------------------------------------------------------------------------
__global__ __launch_bounds__(256, 4)
void conv_first(const float* __restrict__ in, const ushort_t* __restrict__ wp,
                const float* __restrict__ bias, ushort_t* __restrict__ out)
{
    __shared__ float s_raw[2][18][20];
    __shared__ __align__(16) char epi[32768];
    const int tid = threadIdx.x;
    const int x0 = blockIdx.x * 16, y0 = blockIdx.y * 16, b = blockIdx.z;
    {
        float tmp[3];
#pragma unroll
        for (int k = 0; k < 3; ++k) {
            const int idx = tid + k * 256;
            tmp[k] = 0.f;
            if (idx < 648) {
                const int ch = idx / 324, rem = idx - ch * 324;
                const int r = rem / 18, x = rem - r * 18;
                const int gy = y0 - 1 + r, gx = x0 - 1 + x;
                if ((unsigned)gy < HH && (unsigned)gx < WW)
                    tmp[k] = in[((size_t)((b * 2 + ch) * HH + gy)) * WW + gx];
            }
        }
#pragma unroll
        for (int k = 0; k < 3; ++k) {
            const int idx = tid + k * 256;
            if (idx < 648) {
                const int ch = idx / 324, rem = idx - ch * 324;
                const int r = rem / 18, x = rem - r * 18;
                s_raw[ch][r][x] = tmp[k];
            }
        }
    }
    __syncthreads();

    const int lane = tid & 63, w4 = (tid >> 6) * 4;
    const int n = lane & 15, g = lane >> 4;

    V16 af[4];
#pragma unroll
    for (int mt = 0; mt < 4; ++mt)
        af[mt].i4 = *(const i32x4*)(wp + ((size_t)(mt * 64 + lane)) * 8);

    f32x4 acc[4][4];
#pragma unroll
    for (int i = 0; i < 4; ++i)
#pragma unroll
        for (int j = 0; j < 4; ++j) acc[i][j] = 0.f;

#pragma unroll
    for (int nt = 0; nt < 4; ++nt) {
        const int r = w4 + nt;
        V16 bf;
#pragma unroll
        for (int i = 0; i < 8; ++i) {
            const int k = g * 8 + i;
            float v = 0.f;
            if (k < 18) {
                const int ch = (k >= 9) ? 1 : 0;
                const int t = k - ch * 9;
                const int ky = t / 3, kx = t - ky * 3;
                v = s_raw[ch][r + ky][n + kx];
            }
            bf.h[i] = f2b(v);
        }
#pragma unroll
        for (int mt = 0; mt < 4; ++mt)
            acc[nt][mt] = __builtin_amdgcn_mfma_f32_16x16x32_bf16(
                af[mt].v, bf.v, acc[nt][mt], 0, 0, 0);
    }

#pragma unroll
    for (int nt = 0; nt < 4; ++nt) {
        const int row = w4 + nt;
#pragma unroll
        for (int mt = 0; mt < 4; ++mt) {
            const int co0 = mt * 16 + g * 4;
            const float4 bv = *(const float4*)(bias + co0);
            V8 ov;
            ov.h[0] = f2b(acc[nt][mt][0] + bv.x);
            ov.h[1] = f2b(acc[nt][mt][1] + bv.y);
            ov.h[2] = f2b(acc[nt][mt][2] + bv.z);
            ov.h[3] = f2b(acc[nt][mt][3] + bv.w);
            const int c = 2 * mt + (g >> 1);
            const int cpr = c ^ (n & 7);
            *(i32x2*)(epi + row * 2048 + n * 128 + cpr * 16 + (g & 1) * 8) = ov.i2;
        }
    }
    __syncthreads();
#pragma unroll
    for (int r0 = 0; r0 < 4; ++r0) {
        const int row = w4 + r0, y = y0 + row;
#pragma unroll
        for (int j = 0; j < 2; ++j) {
            const int px = (lane >> 3) + 8 * j;
            const int clin = lane & 7;
            const int cpr = clin ^ (px & 7);
            i32x4 v = *(const i32x4*)(epi + row * 2048 + px * 128 + cpr * 16);
            *(i32x4*)(out + ((size_t)((b * HH + y) * WW + x0 + px)) * 64
                          + clin * 8) = v;
        }
    }
}

// ---------------------------------------------------------------------------
// KPN: array-free, d2-grouped, fully compile-time via template recursion.
// No max-subtraction (logits = |core| are small; exp safe in fp32; softmax
// ratio unchanged). Each exp is consumed immediately -> zero private arrays
// (R4's vt[] arrays lived in scratch: 119 MB of spill writes).
// ---------------------------------------------------------------------------
constexpr int isq_(int v) { int r = 0; while ((r + 1) * (r + 1) <= v) ++r; return r; }
constexpr double csqrt_(int x) {
    double g = x ? (double)x : 0.0;
    if (x) for (int i = 0; i < 80; ++i) g = 0.5 * (g + (double)x / g);
    return g;
}
constexpr int tapm_(int W, int d2) {             // multiplicity of d2 (inside taps)
    const int R = W - 1; int c = 0;
    for (int di = -R; di <= R; ++di)
        for (int dj = -R; dj <= R; ++dj)
            if (di * di + dj * dj == d2) ++c;
    return c;
}
constexpr int nout_(int W) {                     // taps outside radius
    const int R = W - 1; int c = 0;
    for (int di = -R; di <= R; ++di)
        for (int dj = -R; dj <= R; ++dj)
            if (di * di + dj * dj > R * R) ++c;
    return c;
}

// Sum of frame taps at squared distance D2 (recursion over di).
template<int W, int D2, int DI>
struct DiSum {
    static constexpr int R = W - 1;
    static __device__ __forceinline__ float run(const float* s_f, int base) {
        float s = 0.f;
        constexpr int rem = D2 - DI * DI;
        if constexpr (rem >= 0) {
            constexpr int sj = isq_(rem >= 0 ? rem : 0);
            if constexpr (sj * sj == rem) {
                s += s_f[base + DI * 48 + sj];
                if constexpr (sj > 0) s += s_f[base + DI * 48 - sj];
            }
        }
        if constexpr (DI < R) s += DiSum<W, D2, DI + 1>::run(s_f, base);
        return s;
    }
};

template<int W, int OFF, int D2>
struct D2Loop {
    static __device__ __forceinline__ void run(const float* cv, const float* s_f,
                                               int base, float& num, float& den) {
        constexpr int m = tapm_(W, D2);
        if constexpr (m > 0) {
            constexpr int lo = isq_(D2);
            float v;
            if constexpr (lo * lo == D2) {
                v = cv[OFF + lo];
            } else {
                constexpr float fr = (float)(csqrt_(D2) - (double)lo);
                v = __builtin_fmaf(fr, cv[OFF + lo + 1] - cv[OFF + lo], cv[OFF + lo]);
            }
            const float e = __expf(v);
            const float S = DiSum<W, D2, -(W - 1)>::run(s_f, base);
            num = __builtin_fmaf(e, S, num);
            den = __builtin_fmaf((float)m, e, den);
        }
        if constexpr (D2 > 0)
            D2Loop<W, OFF, D2 - 1>::run(cv, s_f, base, num, den);
    }
};

template<int W, int OFF>
__device__ __forceinline__ float kpn_section(const float* cv, const float* s_f,
                                             int base)
{
    constexpr int R = W - 1, R2 = R * R;
    float sout = 0.f;                            // outside taps: e = exp(0) = 1
#pragma unroll
    for (int di = -R; di <= R; ++di)
#pragma unroll
        for (int dj = -R; dj <= R; ++dj)
            if (di * di + dj * dj > R2)          // compile-time constant per iter
                sout += s_f[base + di * 48 + dj];
    float num = sout, den = (float)nout_(W);
    D2Loop<W, OFF, R2>::run(cv, s_f, base, num, den);
    return num / den;
}

// ---------------------------------------------------------------------------
// Fused out-conv (64->35, COT=3) + KPN. Batched staging.
// LDS: stage 41472 B (aliased by core px-major 256x37 fp32) + frames 5760 B.
// ---------------------------------------------------------------------------
__global__ __launch_bounds__(256, 3)
void conv_kpn(const ushort_t* __restrict__ in, const ushort_t* __restrict__ wp,
              const float* __restrict__ bias, const float* __restrict__ frames,
              float* __restrict__ out)
{
    __shared__ __align__(16) char smem[41472 + 5760];
    i32x4* s4 = (i32x4*)smem;                    // stage [(r*8+oct)*18+x]
    float* s_core = (float*)smem;                // [px 256][ch 37]
    float* s_f = (float*)(smem + 41472);         // frames 30x48

    const int tid = threadIdx.x;
    const int x0 = blockIdx.x * 16, y0 = blockIdx.y * 16, b = blockIdx.z;

    {
        i32x4 tmp[11];
#pragma unroll
        for (int k = 0; k < 11; ++k) {
            const int idx = tid + k * 256;
            tmp[k] = 0;
            if (idx < 2592) {
                const int oct = idx & 7, p = idx >> 3;
                const int r = p / 18, xx = p - r * 18;
                const int gy = y0 - 1 + r, gx = x0 - 1 + xx;
                if ((unsigned)gy < HH && (unsigned)gx < WW)
                    tmp[k] = *(const i32x4*)(in +
                        ((size_t)((b * HH + gy) * WW + gx)) * 64 + oct * 8);
            }
        }
        float ff[4];
#pragma unroll
        for (int k = 0; k < 4; ++k) {
            const int idx = tid + k * 256;
            ff[k] = 0.f;
            if (idx < 900) {
                const int r = idx / 30, c = idx - r * 30;
                const int y = y0 - 7 + r, x = x0 - 7 + c;
                if ((unsigned)y < HH && (unsigned)x < WW)
                    ff[k] = frames[((size_t)b * HH + y) * WW + x];
            }
        }
#pragma unroll
        for (int k = 0; k < 11; ++k) {
            const int idx = tid + k * 256;
            if (idx < 2592) {
                const int oct = idx & 7, p = idx >> 3;
                const int r = p / 18, xx = p - r * 18;
                s4[(r * 8 + oct) * 18 + xx] = tmp[k];
            }
        }
#pragma unroll
        for (int k = 0; k < 4; ++k) {
            const int idx = tid + k * 256;
            if (idx < 900) {
                const int r = idx / 30, c = idx - r * 30;
                s_f[r * 48 + c] = ff[k];
            }
        }
    }
    __syncthreads();

    const int lane = tid & 63, w4 = (tid >> 6) * 4;
    const int n = lane & 15, g = lane >> 4;

    f32x4 acc[4][3];
#pragma unroll
    for (int i = 0; i < 4; ++i)
#pragma unroll
        for (int j = 0; j < 3; ++j) acc[i][j] = 0.f;

#pragma unroll
    for (int t = 0; t < 9; ++t) {
        const int ky = t / 3, kx = t - ky * 3;
#pragma unroll
        for (int s = 0; s < 2; ++s) {
            V16 bf[4];
#pragma unroll
            for (int nt = 0; nt < 4; ++nt)
                bf[nt].i4 = s4[((w4 + nt + ky) * 8 + s * 4 + g) * 18 + (n + kx)];
#pragma unroll
            for (int mt = 0; mt < 3; ++mt) {
                V16 af;
                af.i4 = *(const i32x4*)(wp +
                    ((size_t)(((t * 2 + s) * 3 + mt) * 64 + lane)) * 8);
#pragma unroll
                for (int nt = 0; nt < 4; ++nt)
                    acc[nt][mt] = __builtin_amdgcn_mfma_f32_16x16x32_bf16(
                        af.v, bf[nt].v, acc[nt][mt], 0, 0, 0);
            }
        }
    }

    __syncthreads();                             // stage reads done; write core
#pragma unroll
    for (int nt = 0; nt < 4; ++nt) {
        const int px = (w4 + nt) * 16 + n;
#pragma unroll
        for (int mt = 0; mt < 3; ++mt) {
#pragma unroll
            for (int r = 0; r < 4; ++r) {
                const int ch = mt * 16 + g * 4 + r;
                if (ch < 35)
                    s_core[px * 37 + ch] = fabsf(acc[nt][mt][r] + bias[ch]);
            }
        }
    }
    __syncthreads();

    const int ty = tid >> 4, tx = tid & 15;
    const int base = (ty + 7) * 48 + (tx + 7);
    const float* cv = s_core + tid * 37;
    float pred = 0.f;
    pred += kpn_section<2, 0>(cv, s_f, base);
    pred += kpn_section<3, 2>(cv, s_f, base);
    pred += kpn_section<4, 5>(cv, s_f, base);
    pred += kpn_section<5, 9>(cv, s_f, base);
    pred += kpn_section<6, 14>(cv, s_f, base);
    pred += kpn_section<7, 20>(cv, s_f, base);
    pred += kpn_section<8, 27>(cv, s_f, base);
    out[((size_t)b * HH + y0 + ty) * WW + x0 + tx] = pred;
}

// ---------------------------------------------------------------------------
extern "C" void kernel_launch(void* const* d_in, const int* in_sizes, int n_in,
                              void* d_out, int out_size, void* d_ws, size_t ws_size,
                              hipStream_t stream)
{
    const float* est     = (const float*)d_in[0];
    const float* data    = (const float*)d_in[1];
    const float* w_first = (const float*)d_in[2];
    const float* b_first = (const float*)d_in[3];
    const float* w1a = (const float*)d_in[4];
    const float* b1a = (const float*)d_in[5];
    const float* w1b = (const float*)d_in[6];
    const float* b1b = (const float*)d_in[7];
    const float* w2a = (const float*)d_in[8];
    const float* b2a = (const float*)d_in[9];
    const float* w2b = (const float*)d_in[10];
    const float* b2b = (const float*)d_in[11];
    const float* w3a = (const float*)d_in[12];
    const float* b3a = (const float*)d_in[13];
    const float* w3b = (const float*)d_in[14];
    const float* b3b = (const float*)d_in[15];
    const float* w_out = (const float*)d_in[16];
    const float* b_out = (const float*)d_in[17];

    ushort_t* X  = (ushort_t*)d_ws;                         // NHWC bf16 (B,H,W,64)
    ushort_t* T  = X + (size_t)BB * HH * WW * 64;
    ushort_t* Wd = T + (size_t)BB * HH * WW * 64;           // repacked weights

    WSrc wsrc;
    wsrc.p[0] = w1a; wsrc.p[1] = w1b; wsrc.p[2] = w2a; wsrc.p[3] = w2b;
    wsrc.p[4] = w3a; wsrc.p[5] = w3b; wsrc.p[6] = w_out; wsrc.p[7] = w_first;

    dim3 blk(256), g(WW / 16, HH / 16, BB);
    repack_k<<<980, 256, 0, stream>>>(wsrc, Wd);
    conv_first<<<g, blk, 0, stream>>>(est, Wd + 248832, b_first, X);
    conv_mfma<true,  false><<<g, blk, 0, stream>>>(X, Wd + 0,      b1a, nullptr, T);
    conv_mfma<false, true ><<<g, blk, 0, stream>>>(T, Wd + 36864,  b1b, X, X);
    conv_mfma<true,  false><<<g, blk, 0, stream>>>(X, Wd + 73728,  b2a, nullptr, T);
    conv_mfma<false, true ><<<g, blk, 0, stream>>>(T, Wd + 110592, b2b, X, X);
    conv_mfma<true,  false><<<g, blk, 0, stream>>>(X, Wd + 147456, b3a, nullptr, T);
    conv_mfma<false, true ><<<g, blk, 0, stream>>>(T, Wd + 184320, b3b, X, X);
    conv_kpn<<<g, blk, 0, stream>>>(X, Wd + 221184, b_out, data, (float*)d_out);
}

// Round 7
// 316.729 us; speedup vs baseline: 4.0656x; 1.4104x over previous
//
#include <hip/hip_runtime.h>

#define HH 384
#define WW 384
#define BB 2

typedef unsigned short ushort_t;
typedef short  s16x8 __attribute__((ext_vector_type(8)));
typedef float  f32x4 __attribute__((ext_vector_type(4)));
typedef int    i32x4 __attribute__((ext_vector_type(4)));
typedef int    i32x2 __attribute__((ext_vector_type(2)));

union V16 { i32x4 i4; s16x8 v; ushort_t h[8]; };
union V8  { i32x2 i2; ushort_t h[4]; };

__device__ __forceinline__ ushort_t f2b(float f) {           // RNE fp32->bf16
    unsigned u = __builtin_bit_cast(unsigned, f);
    u += 0x7fffu + ((u >> 16) & 1u);
    return (ushort_t)(u >> 16);
}
__device__ __forceinline__ float b2f(ushort_t h) {
    return __builtin_bit_cast(float, ((unsigned)h) << 16);
}

// ---------------------------------------------------------------------------
// Weight repack. s-major so each 32-ci chunk is contiguous (LDS-stageable).
// Main convs j=0..5: [s(2)][t(9)][mt(4)][lane(64)][i(8)], 36864 each.
// w_out: [s(2)][t(9)][mt(3)][lane][i]: 27648.  w_first: [mt(4)][lane][i]: 2048.
// ---------------------------------------------------------------------------
struct WSrc { const float* p[8]; };

__global__ __launch_bounds__(256)
void repack_k(WSrc ws, ushort_t* __restrict__ Wd)
{
    const int idx = blockIdx.x * 256 + threadIdx.x;
    float val = 0.f;
    if (idx < 221184) {
        const int j = idx / 36864, rem = idx - j * 36864;
        const int i = rem & 7, lane = (rem >> 3) & 63;
        const int f = rem >> 9;                  // (s*9+t)*4+mt
        const int mt = f & 3, st = f >> 2;
        const int t = st % 9, s = st / 9;
        const int co = mt * 16 + (lane & 15);
        const int ci = s * 32 + (lane >> 4) * 8 + i;
        val = ws.p[j][((size_t)(co * 64 + ci)) * 9 + t];
    } else if (idx < 248832) {
        const int rem = idx - 221184;
        const int i = rem & 7, lane = (rem >> 3) & 63;
        const int f = rem >> 9;                  // (s*9+t)*3+mt
        const int mt = f % 3, st = f / 3;
        const int t = st % 9, s = st / 9;
        const int co = mt * 16 + (lane & 15);
        const int ci = s * 32 + (lane >> 4) * 8 + i;
        val = (co < 35) ? ws.p[6][((size_t)(co * 64 + ci)) * 9 + t] : 0.f;
    } else {
        const int rem = idx - 248832;            // < 2048
        const int i = rem & 7, lane = (rem >> 3) & 63;
        const int mt = rem >> 9;
        const int co = mt * 16 + (lane & 15);
        const int k = (lane >> 4) * 8 + i;
        if (k < 18) {
            const int ch = (k >= 9) ? 1 : 0;
            const int t = k - ch * 9;
            val = ws.p[7][((size_t)(co * 2 + ch)) * 9 + t];
        }
    }
    if (idx < 250880) Wd[idx] = f2b(val);
}

// ---------------------------------------------------------------------------
// Main conv: implicit GEMM, ALL-LDS inner loop.
// LDS: act 41472 B (full 64-ci halo tile) + wgt chunk 36864 B (32 ci).
// Chunk-1 weights prefetched to regs during chunk-0 compute.
// Weight buffer is addressed in 16-B SLOTS (slot = 8 elements): chunk1 of the
// main convs starts at slot 2304 (R6 bug: used element offset as slot offset).
// 78.3 KB -> 2 blocks/CU; (256,2) leaves VGPRs unconstrained (R3 lesson:
// never cap below the ~130 live set — spill goes to HBM scratch).
// ---------------------------------------------------------------------------
template<bool RELU, bool RES>
__global__ __launch_bounds__(256, 2)
void conv_mfma(const ushort_t* __restrict__ in, const ushort_t* __restrict__ wp,
               const float* __restrict__ bias, const ushort_t* __restrict__ res,
               ushort_t* __restrict__ out)
{
    __shared__ __align__(16) char smem[41472 + 36864];
    i32x4* s4 = (i32x4*)smem;                    // act: [(r*8+oct)*18 + x]
    i32x4* sw = (i32x4*)(smem + 41472);          // wgt chunk: [(t*4+mt)*64+lane]

    const int tid = threadIdx.x;
    const int x0 = blockIdx.x * 16, y0 = blockIdx.y * 16, b = blockIdx.z;
    const int lane = tid & 63, w4 = (tid >> 6) * 4;
    const int n = lane & 15, g = lane >> 4;

    // ---- batched staging: act (11 loads) + wgt chunk0 (9 loads) in flight ----
    {
        i32x4 ta[11];
#pragma unroll
        for (int k = 0; k < 11; ++k) {
            const int idx = tid + k * 256;
            ta[k] = 0;
            if (idx < 2592) {
                const int oct = idx & 7, p = idx >> 3;
                const int r = p / 18, xx = p - r * 18;
                const int gy = y0 - 1 + r, gx = x0 - 1 + xx;
                if ((unsigned)gy < HH && (unsigned)gx < WW)
                    ta[k] = *(const i32x4*)(in +
                        ((size_t)((b * HH + gy) * WW + gx)) * 64 + oct * 8);
            }
        }
        i32x4 tw[9];
#pragma unroll
        for (int k = 0; k < 9; ++k)
            tw[k] = *(const i32x4*)(wp + (size_t)(tid + k * 256) * 8);
#pragma unroll
        for (int k = 0; k < 11; ++k) {
            const int idx = tid + k * 256;
            if (idx < 2592) {
                const int oct = idx & 7, p = idx >> 3;
                const int r = p / 18, xx = p - r * 18;
                s4[(r * 8 + oct) * 18 + xx] = ta[k];
            }
        }
#pragma unroll
        for (int k = 0; k < 9; ++k)
            sw[tid + k * 256] = tw[k];
    }
    __syncthreads();

    f32x4 acc[4][4];
#pragma unroll
    for (int i = 0; i < 4; ++i)
#pragma unroll
        for (int j = 0; j < 4; ++j) acc[i][j] = 0.f;

    // prefetch wgt chunk1 into regs (retires behind chunk-0 compute).
    // chunk1 = slots 2304..4607  (element 18432 onward)
    i32x4 pw[9];
#pragma unroll
    for (int k = 0; k < 9; ++k)
        pw[k] = *(const i32x4*)(wp + (size_t)(2304 + tid + k * 256) * 8);

    // ---- chunk 0 (ci 0..31): all-LDS ----
#pragma unroll
    for (int t = 0; t < 9; ++t) {
        const int ky = t / 3, kx = t - ky * 3;
        V16 bf[4];
#pragma unroll
        for (int nt = 0; nt < 4; ++nt)
            bf[nt].i4 = s4[((w4 + nt + ky) * 8 + g) * 18 + (n + kx)];
#pragma unroll
        for (int mt = 0; mt < 4; ++mt) {
            V16 af; af.i4 = sw[(t * 4 + mt) * 64 + lane];
#pragma unroll
            for (int nt = 0; nt < 4; ++nt)
                acc[nt][mt] = __builtin_amdgcn_mfma_f32_16x16x32_bf16(
                    af.v, bf[nt].v, acc[nt][mt], 0, 0, 0);
        }
    }

    __syncthreads();                             // chunk0 wgt reads done
#pragma unroll
    for (int k = 0; k < 9; ++k)
        sw[tid + k * 256] = pw[k];
    __syncthreads();

    // ---- chunk 1 (ci 32..63) ----
#pragma unroll
    for (int t = 0; t < 9; ++t) {
        const int ky = t / 3, kx = t - ky * 3;
        V16 bf[4];
#pragma unroll
        for (int nt = 0; nt < 4; ++nt)
            bf[nt].i4 = s4[((w4 + nt + ky) * 8 + 4 + g) * 18 + (n + kx)];
#pragma unroll
        for (int mt = 0; mt < 4; ++mt) {
            V16 af; af.i4 = sw[(t * 4 + mt) * 64 + lane];
#pragma unroll
            for (int nt = 0; nt < 4; ++nt)
                acc[nt][mt] = __builtin_amdgcn_mfma_f32_16x16x32_bf16(
                    af.v, bf[nt].v, acc[nt][mt], 0, 0, 0);
        }
    }

    // ---- transpose epilogue (aliases act region) ----
    __syncthreads();
#pragma unroll
    for (int nt = 0; nt < 4; ++nt) {
        const int row = w4 + nt;
#pragma unroll
        for (int mt = 0; mt < 4; ++mt) {
            const int co0 = mt * 16 + g * 4;
            const float4 bv = *(const float4*)(bias + co0);
            float vv[4] = {acc[nt][mt][0] + bv.x, acc[nt][mt][1] + bv.y,
                           acc[nt][mt][2] + bv.z, acc[nt][mt][3] + bv.w};
            V8 ov;
#pragma unroll
            for (int r = 0; r < 4; ++r)
                ov.h[r] = f2b(RELU ? fmaxf(vv[r], 0.f) : vv[r]);
            const int c = 2 * mt + (g >> 1);
            const int cpr = c ^ (n & 7);
            *(i32x2*)(smem + row * 2048 + n * 128 + cpr * 16 + (g & 1) * 8) = ov.i2;
        }
    }
    __syncthreads();
    // readback: 64 lanes x 16B = 1 KB contiguous per wave instruction;
    // residual added here (same coalesced pattern).
#pragma unroll
    for (int r0 = 0; r0 < 4; ++r0) {
        const int row = w4 + r0, y = y0 + row;
#pragma unroll
        for (int j = 0; j < 2; ++j) {
            const int px = (lane >> 3) + 8 * j;
            const int clin = lane & 7;
            const int cpr = clin ^ (px & 7);
            V16 v;
            v.i4 = *(const i32x4*)(smem + row * 2048 + px * 128 + cpr * 16);
            const size_t goff = ((size_t)((b * HH + y) * WW + x0 + px)) * 64
                                + clin * 8;
            if (RES) {
                V16 rv;
                rv.i4 = *(const i32x4*)(res + goff);
#pragma unroll
                for (int e = 0; e < 8; ++e)
                    v.h[e] = f2b(b2f(v.h[e]) + b2f(rv.h[e]));
            }
            *(i32x4*)(out + goff) = v.i4;
        }
    }
}

// ---------------------------------------------------------------------------
// First conv: CI=2 fp32 NCHW, K=18 padded to 32, transpose epilogue.
// ---------------------------------------------------------------------------
__global__ __launch_bounds__(256, 4)
void conv_first(const float* __restrict__ in, const ushort_t* __restrict__ wp,
                const float* __restrict__ bias, ushort_t* __restrict__ out)
{
    __shared__ float s_raw[2][18][20];
    __shared__ __align__(16) char epi[32768];
    const int tid = threadIdx.x;
    const int x0 = blockIdx.x * 16, y0 = blockIdx.y * 16, b = blockIdx.z;
    {
        float tmp[3];
#pragma unroll
        for (int k = 0; k < 3; ++k) {
            const int idx = tid + k * 256;
            tmp[k] = 0.f;
            if (idx < 648) {
                const int ch = idx / 324, rem = idx - ch * 324;
                const int r = rem / 18, x = rem - r * 18;
                const int gy = y0 - 1 + r, gx = x0 - 1 + x;
                if ((unsigned)gy < HH && (unsigned)gx < WW)
                    tmp[k] = in[((size_t)((b * 2 + ch) * HH + gy)) * WW + gx];
            }
        }
#pragma unroll
        for (int k = 0; k < 3; ++k) {
            const int idx = tid + k * 256;
            if (idx < 648) {
                const int ch = idx / 324, rem = idx - ch * 324;
                const int r = rem / 18, x = rem - r * 18;
                s_raw[ch][r][x] = tmp[k];
            }
        }
    }
    __syncthreads();

    const int lane = tid & 63, w4 = (tid >> 6) * 4;
    const int n = lane & 15, g = lane >> 4;

    V16 af[4];
#pragma unroll
    for (int mt = 0; mt < 4; ++mt)
        af[mt].i4 = *(const i32x4*)(wp + ((size_t)(mt * 64 + lane)) * 8);

    f32x4 acc[4][4];
#pragma unroll
    for (int i = 0; i < 4; ++i)
#pragma unroll
        for (int j = 0; j < 4; ++j) acc[i][j] = 0.f;

#pragma unroll
    for (int nt = 0; nt < 4; ++nt) {
        const int r = w4 + nt;
        V16 bf;
#pragma unroll
        for (int i = 0; i < 8; ++i) {
            const int k = g * 8 + i;
            float v = 0.f;
            if (k < 18) {
                const int ch = (k >= 9) ? 1 : 0;
                const int t = k - ch * 9;
                const int ky = t / 3, kx = t - ky * 3;
                v = s_raw[ch][r + ky][n + kx];
            }
            bf.h[i] = f2b(v);
        }
#pragma unroll
        for (int mt = 0; mt < 4; ++mt)
            acc[nt][mt] = __builtin_amdgcn_mfma_f32_16x16x32_bf16(
                af[mt].v, bf.v, acc[nt][mt], 0, 0, 0);
    }

#pragma unroll
    for (int nt = 0; nt < 4; ++nt) {
        const int row = w4 + nt;
#pragma unroll
        for (int mt = 0; mt < 4; ++mt) {
            const int co0 = mt * 16 + g * 4;
            const float4 bv = *(const float4*)(bias + co0);
            V8 ov;
            ov.h[0] = f2b(acc[nt][mt][0] + bv.x);
            ov.h[1] = f2b(acc[nt][mt][1] + bv.y);
            ov.h[2] = f2b(acc[nt][mt][2] + bv.z);
            ov.h[3] = f2b(acc[nt][mt][3] + bv.w);
            const int c = 2 * mt + (g >> 1);
            const int cpr = c ^ (n & 7);
            *(i32x2*)(epi + row * 2048 + n * 128 + cpr * 16 + (g & 1) * 8) = ov.i2;
        }
    }
    __syncthreads();
#pragma unroll
    for (int r0 = 0; r0 < 4; ++r0) {
        const int row = w4 + r0, y = y0 + row;
#pragma unroll
        for (int j = 0; j < 2; ++j) {
            const int px = (lane >> 3) + 8 * j;
            const int clin = lane & 7;
            const int cpr = clin ^ (px & 7);
            i32x4 v = *(const i32x4*)(epi + row * 2048 + px * 128 + cpr * 16);
            *(i32x4*)(out + ((size_t)((b * HH + y) * WW + x0 + px)) * 64
                          + clin * 8) = v;
        }
    }
}

// ---------------------------------------------------------------------------
// KPN: array-free, d2-grouped, compile-time recursion (R5 — fixed the scratch
// spill). No max-subtraction: softmax ratio unchanged, |core| logits are small.
// ---------------------------------------------------------------------------
constexpr int isq_(int v) { int r = 0; while ((r + 1) * (r + 1) <= v) ++r; return r; }
constexpr double csqrt_(int x) {
    double g = x ? (double)x : 0.0;
    if (x) for (int i = 0; i < 80; ++i) g = 0.5 * (g + (double)x / g);
    return g;
}
constexpr int tapm_(int W, int d2) {
    const int R = W - 1; int c = 0;
    for (int di = -R; di <= R; ++di)
        for (int dj = -R; dj <= R; ++dj)
            if (di * di + dj * dj == d2) ++c;
    return c;
}
constexpr int nout_(int W) {
    const int R = W - 1; int c = 0;
    for (int di = -R; di <= R; ++di)
        for (int dj = -R; dj <= R; ++dj)
            if (di * di + dj * dj > R * R) ++c;
    return c;
}

template<int W, int D2, int DI>
struct DiSum {
    static constexpr int R = W - 1;
    static __device__ __forceinline__ float run(const float* s_f, int base) {
        float s = 0.f;
        constexpr int rem = D2 - DI * DI;
        if constexpr (rem >= 0) {
            constexpr int sj = isq_(rem >= 0 ? rem : 0);
            if constexpr (sj * sj == rem) {
                s += s_f[base + DI * 48 + sj];
                if constexpr (sj > 0) s += s_f[base + DI * 48 - sj];
            }
        }
        if constexpr (DI < R) s += DiSum<W, D2, DI + 1>::run(s_f, base);
        return s;
    }
};

template<int W, int OFF, int D2>
struct D2Loop {
    static __device__ __forceinline__ void run(const float* cv, const float* s_f,
                                               int base, float& num, float& den) {
        constexpr int m = tapm_(W, D2);
        if constexpr (m > 0) {
            constexpr int lo = isq_(D2);
            float v;
            if constexpr (lo * lo == D2) {
                v = cv[OFF + lo];
            } else {
                constexpr float fr = (float)(csqrt_(D2) - (double)lo);
                v = __builtin_fmaf(fr, cv[OFF + lo + 1] - cv[OFF + lo], cv[OFF + lo]);
            }
            const float e = __expf(v);
            const float S = DiSum<W, D2, -(W - 1)>::run(s_f, base);
            num = __builtin_fmaf(e, S, num);
            den = __builtin_fmaf((float)m, e, den);
        }
        if constexpr (D2 > 0)
            D2Loop<W, OFF, D2 - 1>::run(cv, s_f, base, num, den);
    }
};

template<int W, int OFF>
__device__ __forceinline__ float kpn_section(const float* cv, const float* s_f,
                                             int base)
{
    constexpr int R = W - 1, R2 = R * R;
    float sout = 0.f;                            // outside taps: e = exp(0) = 1
#pragma unroll
    for (int di = -R; di <= R; ++di)
#pragma unroll
        for (int dj = -R; dj <= R; ++dj)
            if (di * di + dj * dj > R2)
                sout += s_f[base + di * 48 + dj];
    float num = sout, den = (float)nout_(W);
    D2Loop<W, OFF, R2>::run(cv, s_f, base, num, den);
    return num / den;
}

// ---------------------------------------------------------------------------
// Fused out-conv (64->35, COT=3) + KPN, all-LDS inner loop.
// LDS: stage 41472 (aliased by core 256x37 fp32) + frames 5760 + wgt 27648.
// w_out chunk1 = slots 1728..3455 (element 13824 onward).
// ---------------------------------------------------------------------------
__global__ __launch_bounds__(256, 2)
void conv_kpn(const ushort_t* __restrict__ in, const ushort_t* __restrict__ wp,
              const float* __restrict__ bias, const float* __restrict__ frames,
              float* __restrict__ out)
{
    __shared__ __align__(16) char smem[41472 + 5760 + 27648];
    i32x4* s4 = (i32x4*)smem;                    // stage [(r*8+oct)*18+x]
    float* s_core = (float*)smem;                // [px 256][ch 37]
    float* s_f = (float*)(smem + 41472);         // frames 30x48
    i32x4* sw = (i32x4*)(smem + 41472 + 5760);   // wgt chunk: 1728 slots

    const int tid = threadIdx.x;
    const int x0 = blockIdx.x * 16, y0 = blockIdx.y * 16, b = blockIdx.z;

    {
        i32x4 ta[11];
#pragma unroll
        for (int k = 0; k < 11; ++k) {
            const int idx = tid + k * 256;
            ta[k] = 0;
            if (idx < 2592) {
                const int oct = idx & 7, p = idx >> 3;
                const int r = p / 18, xx = p - r * 18;
                const int gy = y0 - 1 + r, gx = x0 - 1 + xx;
                if ((unsigned)gy < HH && (unsigned)gx < WW)
                    ta[k] = *(const i32x4*)(in +
                        ((size_t)((b * HH + gy) * WW + gx)) * 64 + oct * 8);
            }
        }
        float ff[4];
#pragma unroll
        for (int k = 0; k < 4; ++k) {
            const int idx = tid + k * 256;
            ff[k] = 0.f;
            if (idx < 900) {
                const int r = idx / 30, c = idx - r * 30;
                const int y = y0 - 7 + r, x = x0 - 7 + c;
                if ((unsigned)y < HH && (unsigned)x < WW)
                    ff[k] = frames[((size_t)b * HH + y) * WW + x];
            }
        }
        i32x4 tw[7];
#pragma unroll
        for (int k = 0; k < 7; ++k) {
            const int idx = tid + k * 256;
            tw[k] = 0;
            if (idx < 1728)
                tw[k] = *(const i32x4*)(wp + (size_t)idx * 8);
        }
#pragma unroll
        for (int k = 0; k < 11; ++k) {
            const int idx = tid + k * 256;
            if (idx < 2592) {
                const int oct = idx & 7, p = idx >> 3;
                const int r = p / 18, xx = p - r * 18;
                s4[(r * 8 + oct) * 18 + xx] = ta[k];
            }
        }
#pragma unroll
        for (int k = 0; k < 4; ++k) {
            const int idx = tid + k * 256;
            if (idx < 900) {
                const int r = idx / 30, c = idx - r * 30;
                s_f[r * 48 + c] = ff[k];
            }
        }
#pragma unroll
        for (int k = 0; k < 7; ++k) {
            const int idx = tid + k * 256;
            if (idx < 1728) sw[idx] = tw[k];
        }
    }
    __syncthreads();

    const int lane = tid & 63, w4 = (tid >> 6) * 4;
    const int n = lane & 15, g = lane >> 4;

    f32x4 acc[4][3];
#pragma unroll
    for (int i = 0; i < 4; ++i)
#pragma unroll
        for (int j = 0; j < 3; ++j) acc[i][j] = 0.f;

    // prefetch wgt chunk1 (slots 1728..3455)
    i32x4 pw[7];
#pragma unroll
    for (int k = 0; k < 7; ++k) {
        const int idx = tid + k * 256;
        pw[k] = 0;
        if (idx < 1728)
            pw[k] = *(const i32x4*)(wp + (size_t)(1728 + idx) * 8);
    }

#pragma unroll
    for (int t = 0; t < 9; ++t) {
        const int ky = t / 3, kx = t - ky * 3;
        V16 bf[4];
#pragma unroll
        for (int nt = 0; nt < 4; ++nt)
            bf[nt].i4 = s4[((w4 + nt + ky) * 8 + g) * 18 + (n + kx)];
#pragma unroll
        for (int mt = 0; mt < 3; ++mt) {
            V16 af; af.i4 = sw[(t * 3 + mt) * 64 + lane];
#pragma unroll
            for (int nt = 0; nt < 4; ++nt)
                acc[nt][mt] = __builtin_amdgcn_mfma_f32_16x16x32_bf16(
                    af.v, bf[nt].v, acc[nt][mt], 0, 0, 0);
        }
    }

    __syncthreads();
#pragma unroll
    for (int k = 0; k < 7; ++k) {
        const int idx = tid + k * 256;
        if (idx < 1728) sw[idx] = pw[k];
    }
    __syncthreads();

#pragma unroll
    for (int t = 0; t < 9; ++t) {
        const int ky = t / 3, kx = t - ky * 3;
        V16 bf[4];
#pragma unroll
        for (int nt = 0; nt < 4; ++nt)
            bf[nt].i4 = s4[((w4 + nt + ky) * 8 + 4 + g) * 18 + (n + kx)];
#pragma unroll
        for (int mt = 0; mt < 3; ++mt) {
            V16 af; af.i4 = sw[(t * 3 + mt) * 64 + lane];
#pragma unroll
            for (int nt = 0; nt < 4; ++nt)
                acc[nt][mt] = __builtin_amdgcn_mfma_f32_16x16x32_bf16(
                    af.v, bf[nt].v, acc[nt][mt], 0, 0, 0);
        }
    }

    __syncthreads();                             // stage reads done; write core
#pragma unroll
    for (int nt = 0; nt < 4; ++nt) {
        const int px = (w4 + nt) * 16 + n;
#pragma unroll
        for (int mt = 0; mt < 3; ++mt) {
#pragma unroll
            for (int r = 0; r < 4; ++r) {
                const int ch = mt * 16 + g * 4 + r;
                if (ch < 35)
                    s_core[px * 37 + ch] = fabsf(acc[nt][mt][r] + bias[ch]);
            }
        }
    }
    __syncthreads();

    const int ty = tid >> 4, tx = tid & 15;
    const int base = (ty + 7) * 48 + (tx + 7);
    const float* cv = s_core + tid * 37;
    float pred = 0.f;
    pred += kpn_section<2, 0>(cv, s_f, base);
    pred += kpn_section<3, 2>(cv, s_f, base);
    pred += kpn_section<4, 5>(cv, s_f, base);
    pred += kpn_section<5, 9>(cv, s_f, base);
    pred += kpn_section<6, 14>(cv, s_f, base);
    pred += kpn_section<7, 20>(cv, s_f, base);
    pred += kpn_section<8, 27>(cv, s_f, base);
    out[((size_t)b * HH + y0 + ty) * WW + x0 + tx] = pred;
}

// ---------------------------------------------------------------------------
extern "C" void kernel_launch(void* const* d_in, const int* in_sizes, int n_in,
                              void* d_out, int out_size, void* d_ws, size_t ws_size,
                              hipStream_t stream)
{
    const float* est     = (const float*)d_in[0];
    const float* data    = (const float*)d_in[1];
    const float* w_first = (const float*)d_in[2];
    const float* b_first = (const float*)d_in[3];
    const float* w1a = (const float*)d_in[4];
    const float* b1a = (const float*)d_in[5];
    const float* w1b = (const float*)d_in[6];
    const float* b1b = (const float*)d_in[7];
    const float* w2a = (const float*)d_in[8];
    const float* b2a = (const float*)d_in[9];
    const float* w2b = (const float*)d_in[10];
    const float* b2b = (const float*)d_in[11];
    const float* w3a = (const float*)d_in[12];
    const float* b3a = (const float*)d_in[13];
    const float* w3b = (const float*)d_in[14];
    const float* b3b = (const float*)d_in[15];
    const float* w_out = (const float*)d_in[16];
    const float* b_out = (const float*)d_in[17];

    ushort_t* X  = (ushort_t*)d_ws;                         // NHWC bf16 (B,H,W,64)
    ushort_t* T  = X + (size_t)BB * HH * WW * 64;
    ushort_t* Wd = T + (size_t)BB * HH * WW * 64;           // repacked weights

    WSrc wsrc;
    wsrc.p[0] = w1a; wsrc.p[1] = w1b; wsrc.p[2] = w2a; wsrc.p[3] = w2b;
    wsrc.p[4] = w3a; wsrc.p[5] = w3b; wsrc.p[6] = w_out; wsrc.p[7] = w_first;

    dim3 blk(256), g(WW / 16, HH / 16, BB);
    repack_k<<<980, 256, 0, stream>>>(wsrc, Wd);
    conv_first<<<g, blk, 0, stream>>>(est, Wd + 248832, b_first, X);
    conv_mfma<true,  false><<<g, blk, 0, stream>>>(X, Wd + 0,      b1a, nullptr, T);
    conv_mfma<false, true ><<<g, blk, 0, stream>>>(T, Wd + 36864,  b1b, X, X);
    conv_mfma<true,  false><<<g, blk, 0, stream>>>(X, Wd + 73728,  b2a, nullptr, T);
    conv_mfma<false, true ><<<g, blk, 0, stream>>>(T, Wd + 110592, b2b, X, X);
    conv_mfma<true,  false><<<g, blk, 0, stream>>>(X, Wd + 147456, b3a, nullptr, T);
    conv_mfma<false, true ><<<g, blk, 0, stream>>>(T, Wd + 184320, b3b, X, X);
    conv_kpn<<<g, blk, 0, stream>>>(X, Wd + 221184, b_out, data, (float*)d_out);
}